// Round 2
// baseline (1310.287 us; speedup 1.0000x reference)
//
#include <hip/hip_runtime.h>
#include <stdint.h>

typedef int   v4i  __attribute__((ext_vector_type(4)));
typedef int   v16i __attribute__((ext_vector_type(16)));
typedef float v4f  __attribute__((ext_vector_type(4)));

constexpr int M = 256, N = 28672, K = 8192;
constexpr int BN = 64, BK = 64;
constexpr int KITERS = K / BK;  // 128
// q is stored pre-tiled: 128 kblocks x 16384 bytes; kblock image is exactly the
// A-tile LDS layout: slot(g=row>>5, s=kk>>4, r=row&31) = g*128 + s*32 + r, 16B/slot.

// ---------------------------------------------------------------------------
// Kernel 1: per-token int8 quant (x arrives as float32 per harness dtype rules)
// ---------------------------------------------------------------------------
__global__ __launch_bounds__(256) void quant_kernel(
    const float* __restrict__ x, int8_t* __restrict__ q,
    float* __restrict__ scales)
{
  const int m = blockIdx.x, t = threadIdx.x;
  const float* xr = x + (size_t)m * K;

  v4f v[8];
  float amax = 0.0f;
#pragma unroll
  for (int i = 0; i < 8; ++i) {
    v[i] = *(const v4f*)(xr + (i * 256 + t) * 4);  // coalesced float4
#pragma unroll
    for (int e = 0; e < 4; ++e) amax = fmaxf(amax, fabsf(v[i][e]));
  }
#pragma unroll
  for (int off = 32; off >= 1; off >>= 1)
    amax = fmaxf(amax, __shfl_xor(amax, off, 64));
  __shared__ float wmax[4];
  if ((t & 63) == 0) wmax[t >> 6] = amax;
  __syncthreads();
  amax = fmaxf(fmaxf(wmax[0], wmax[1]), fmaxf(wmax[2], wmax[3]));

  const float s = fmaxf(amax, 1e-5f) / 127.0f;  // IEEE div, matches ref
  if (t == 0) scales[m] = s;

  // element k = (i*256+t)*4 + e  ->  kblock = i*16 + (t>>4), s4 = (t>>2)&3,
  // byte-in-16B-chunk = (t&3)*4
  const int s4 = (t >> 2) & 3;
  const size_t slotoff =
      (size_t)((m >> 5) * 128 + s4 * 32 + (m & 31)) * 16 + (t & 3) * 4;
#pragma unroll
  for (int i = 0; i < 8; ++i) {
    const int b0 = __float2int_rn(v[i][0] / s) & 255;
    const int b1 = __float2int_rn(v[i][1] / s) & 255;
    const int b2 = __float2int_rn(v[i][2] / s) & 255;
    const int b3 = __float2int_rn(v[i][3] / s);
    const int pk = b0 | (b1 << 8) | (b2 << 16) | (b3 << 24);
    const int kblock = i * 16 + (t >> 4);
    *(int*)(q + (size_t)kblock * 16384 + slotoff) = pk;
  }
}

// ---------------------------------------------------------------------------
// Kernel 2: int8 GEMM. A(int8, pre-tiled) via global_load_lds; B(int32 weight)
// via VGPR load -> pack to int8 -> ds_write. mfma_i32_32x32x32_i8.
// Fragment-order LDS: operand read = base + lane*16 (conflict-free b128).
// ---------------------------------------------------------------------------
__device__ __forceinline__ void gload16(const void* gsrc, void* ldst) {
  __builtin_amdgcn_global_load_lds(
      (const __attribute__((address_space(1))) void*)gsrc,
      (__attribute__((address_space(3))) void*)ldst, 16, 0, 0);
}

__global__ __launch_bounds__(256, 2) void gemm_kernel(
    const int8_t* __restrict__ q, const int* __restrict__ wgt,
    const float* __restrict__ ascale, const float* __restrict__ cscale,
    const float* __restrict__ bias, float* __restrict__ out)
{
  __shared__ __align__(16) int8_t Abuf[2][16384];
  __shared__ __align__(16) int8_t Bbuf[2][4096];
  __shared__ float ldsS[256];

  const int tid  = threadIdx.x;
  const int lane = tid & 63;
  const int wv   = tid >> 6;
  const int n0   = blockIdx.x * BN;

  ldsS[tid] = ascale[tid];  // M == 256 == blockDim.x

  // B load mapping (coalesced): instr j covers rows wv*16 + j*4 + (lane>>4),
  // ints (lane&15)*4 .. +4  -> 4 contiguous 256B segments per instruction.
  const int brow0 = wv * 16 + (lane >> 4);
  const int* bsrc = wgt + (size_t)(n0 + brow0) * K + (lane & 15) * 4;

  v4i bv[4];
  auto loadB = [&](int it) {
#pragma unroll
    for (int j = 0; j < 4; ++j)
      bv[j] = *(const v4i*)(bsrc + (size_t)j * 4 * K + it * 64);
  };
  auto writeB = [&](int8_t* Bb) {
#pragma unroll
    for (int j = 0; j < 4; ++j) {
      const int pk = (bv[j][0] & 255) | ((bv[j][1] & 255) << 8) |
                     ((bv[j][2] & 255) << 16) | (bv[j][3] << 24);
      const int R = brow0 + j * 4;
      *(int*)(Bb + (R >> 5) * 2048 + ((lane & 15) >> 2) * 512 + (R & 31) * 16 +
              (lane & 3) * 4) = pk;
    }
  };
  auto stageA = [&](int it, int8_t* Ab) {
#pragma unroll
    for (int rr = 0; rr < 4; ++rr)
      gload16(q + (size_t)it * 16384 + (rr * 256 + tid) * 16,
              Ab + (rr * 256 + tid) * 16);
  };

  // prologue
  loadB(0);
  stageA(0, &Abuf[0][0]);
  writeB(&Bbuf[0][0]);

  v16i acc[2][2];
#pragma unroll
  for (int i = 0; i < 2; ++i)
#pragma unroll
    for (int j = 0; j < 2; ++j)
#pragma unroll
      for (int e = 0; e < 16; ++e) acc[i][j][e] = 0;

  for (int it = 0; it < KITERS; ++it) {
    __syncthreads();  // buffer p ready (A staged, B packed+written), prev reads done
    const int p = it & 1;
    if (it + 1 < KITERS) {
      loadB(it + 1);                     // global->VGPR (issued first: pack waits only these)
      stageA(it + 1, &Abuf[p ^ 1][0]);   // global->LDS async
    }
    const int8_t* Ab = &Abuf[p][0];
    const int8_t* Bb = &Bbuf[p][0];
    const int lb = lane * 16;
#pragma unroll
    for (int ks = 0; ks < 2; ++ks) {
      const v4i a0 = *(const v4i*)(Ab + (2 * wv + 0) * 2048 + ks * 1024 + lb);
      const v4i a1 = *(const v4i*)(Ab + (2 * wv + 1) * 2048 + ks * 1024 + lb);
      const v4i b0 = *(const v4i*)(Bb + 0 * 2048 + ks * 1024 + lb);
      const v4i b1 = *(const v4i*)(Bb + 1 * 2048 + ks * 1024 + lb);
      acc[0][0] = __builtin_amdgcn_mfma_i32_32x32x32_i8(a0, b0, acc[0][0], 0, 0, 0);
      acc[0][1] = __builtin_amdgcn_mfma_i32_32x32x32_i8(a0, b1, acc[0][1], 0, 0, 0);
      acc[1][0] = __builtin_amdgcn_mfma_i32_32x32x32_i8(a1, b0, acc[1][0], 0, 0, 0);
      acc[1][1] = __builtin_amdgcn_mfma_i32_32x32x32_i8(a1, b1, acc[1][1], 0, 0, 0);
    }
    if (it + 1 < KITERS) writeB(&Bbuf[p ^ 1][0]);  // pack after compute (loads landed)
  }

  // epilogue: out[m,n] = acc * ascale[m] * cscale[n] + bias[n]
  // 32x32 C/D mapping (m74/m101): col = lane&31, row = (reg&3)+8*(reg>>2)+4*(lane>>5)
#pragma unroll
  for (int mi = 0; mi < 2; ++mi)
#pragma unroll
    for (int ni = 0; ni < 2; ++ni) {
      const int n_g = n0 + ni * 32 + (lane & 31);
      const float csn = cscale[n_g];
      const float bn  = bias[n_g];
      const int mbase = 64 * wv + mi * 32 + 4 * (lane >> 5);
#pragma unroll
      for (int reg = 0; reg < 16; ++reg) {
        const int mrow = mbase + (reg & 3) + 8 * (reg >> 2);
        out[(size_t)mrow * N + n_g] =
            (float)acc[mi][ni][reg] * ldsS[mrow] * csn + bn;
      }
    }
}

// ---------------------------------------------------------------------------
extern "C" void kernel_launch(void* const* d_in, const int* in_sizes, int n_in,
                              void* d_out, int out_size, void* d_ws, size_t ws_size,
                              hipStream_t stream) {
  const float* x      = (const float*)d_in[0];   // f16 in ref -> f32 on device
  const int*   wgt    = (const int*)d_in[1];     // int8 in ref -> int32 on device
  const float* cscale = (const float*)d_in[2];
  const float* bias   = (const float*)d_in[3];   // f16 in ref -> f32 on device
  float* out = (float*)d_out;

  int8_t* q      = (int8_t*)d_ws;                            // 2 MB, pre-tiled
  float*  ascale = (float*)((int8_t*)d_ws + (size_t)M * K);  // 256 f32

  quant_kernel<<<M, 256, 0, stream>>>(x, q, ascale);
  gemm_kernel<<<N / BN, 256, 0, stream>>>(q, wgt, ascale, cscale, bias, out);
}

// Round 3
// 1247.516 us; speedup vs baseline: 1.0503x; 1.0503x over previous
//
#include <hip/hip_runtime.h>
#include <stdint.h>

typedef int   v4i  __attribute__((ext_vector_type(4)));
typedef int   v16i __attribute__((ext_vector_type(16)));
typedef float v4f  __attribute__((ext_vector_type(4)));

constexpr int M = 256, N = 28672, K = 8192;
constexpr int BN = 64, BK = 64;
constexpr int KITERS = K / BK;  // 128
// q is stored pre-tiled: 128 kblocks x 16384 bytes; kblock image is exactly the
// MFMA A-fragment order: addr(g, ks, lane) = g*2048 + ks*1024 + lane*16.
// => A fragments are direct, fully-coalesced global dwordx4 loads (L2-resident).

// ---------------------------------------------------------------------------
// Kernel 1: per-token int8 quant (x arrives as float32 per harness dtype rules)
// ---------------------------------------------------------------------------
__global__ __launch_bounds__(256) void quant_kernel(
    const float* __restrict__ x, int8_t* __restrict__ q,
    float* __restrict__ scales)
{
  const int m = blockIdx.x, t = threadIdx.x;
  const float* xr = x + (size_t)m * K;

  v4f v[8];
  float amax = 0.0f;
#pragma unroll
  for (int i = 0; i < 8; ++i) {
    v[i] = *(const v4f*)(xr + (i * 256 + t) * 4);  // coalesced float4
#pragma unroll
    for (int e = 0; e < 4; ++e) amax = fmaxf(amax, fabsf(v[i][e]));
  }
#pragma unroll
  for (int off = 32; off >= 1; off >>= 1)
    amax = fmaxf(amax, __shfl_xor(amax, off, 64));
  __shared__ float wmax[4];
  if ((t & 63) == 0) wmax[t >> 6] = amax;
  __syncthreads();
  amax = fmaxf(fmaxf(wmax[0], wmax[1]), fmaxf(wmax[2], wmax[3]));

  const float s = fmaxf(amax, 1e-5f) / 127.0f;  // IEEE div, matches ref
  if (t == 0) scales[m] = s;

  // element k = (i*256+t)*4 + e -> kblock = i*16 + (t>>4), s4 = (t>>2)&3
  const int s4 = (t >> 2) & 3;
  const size_t slotoff =
      (size_t)((m >> 5) * 128 + s4 * 32 + (m & 31)) * 16 + (t & 3) * 4;
#pragma unroll
  for (int i = 0; i < 8; ++i) {
    const int b0 = __float2int_rn(v[i][0] / s) & 255;
    const int b1 = __float2int_rn(v[i][1] / s) & 255;
    const int b2 = __float2int_rn(v[i][2] / s) & 255;
    const int b3 = __float2int_rn(v[i][3] / s);
    const int pk = b0 | (b1 << 8) | (b2 << 16) | (b3 << 24);
    const int kblock = i * 16 + (t >> 4);
    *(int*)(q + (size_t)kblock * 16384 + slotoff) = pk;
  }
}

// ---------------------------------------------------------------------------
// Kernel 2: int8 GEMM. A fragments: global->VGPR register double-buffer
// (q pre-tiled, L2-resident). B (int32 weight, HBM stream): VGPR load ->
// pack int8 -> ds_write into dbuf LDS (fragment order, conflict-free b128).
// LDS = 9.25 KB -> 3 blocks/CU for latency hiding on the B stream.
// ---------------------------------------------------------------------------
__global__ __launch_bounds__(256, 3) void gemm_kernel(
    const int8_t* __restrict__ q, const int* __restrict__ wgt,
    const float* __restrict__ ascale, const float* __restrict__ cscale,
    const float* __restrict__ bias, float* __restrict__ out)
{
  __shared__ __align__(16) int8_t Bbuf[2][4096];
  __shared__ float ldsS[256];

  const int tid  = threadIdx.x;
  const int lane = tid & 63;
  const int wv   = tid >> 6;
  const int n0   = blockIdx.x * BN;

  ldsS[tid] = ascale[tid];  // M == 256 == blockDim.x

  // B load mapping (coalesced): instr j covers rows wv*16 + j*4 + (lane>>4),
  // each row: 16 lanes x 16 ints = 1 KB contiguous.
  const int brow0 = wv * 16 + (lane >> 4);
  const int* bsrc = wgt + (size_t)(n0 + brow0) * K + (lane & 15) * 4;

  v4i bv[4];
  auto loadB = [&](int it) {
#pragma unroll
    for (int j = 0; j < 4; ++j)
      bv[j] = *(const v4i*)(bsrc + (size_t)j * 4 * K + it * 64);
  };
  auto writeB = [&](int8_t* Bb) {
#pragma unroll
    for (int j = 0; j < 4; ++j) {
      const int pk = (bv[j][0] & 255) | ((bv[j][1] & 255) << 8) |
                     ((bv[j][2] & 255) << 16) | (bv[j][3] << 24);
      const int R = brow0 + j * 4;
      *(int*)(Bb + (R >> 5) * 2048 + ((lane & 15) >> 2) * 512 + (R & 31) * 16 +
              (lane & 3) * 4) = pk;
    }
  };

  // A fragments straight from pre-tiled q (1 KB contiguous per wave-instr).
  const int8_t* abase = q + (size_t)(2 * wv) * 2048 + lane * 16;
  v4i a_cur[2][2], a_nxt[2][2];
  auto loadA = [&](int it, v4i (*dst)[2]) {
#pragma unroll
    for (int mi = 0; mi < 2; ++mi)
#pragma unroll
      for (int ks = 0; ks < 2; ++ks)
        dst[mi][ks] =
            *(const v4i*)(abase + (size_t)it * 16384 + mi * 2048 + ks * 1024);
  };

  // prologue: B(0) -> LDS buf0, A(0) -> regs
  loadB(0);
  loadA(0, a_cur);
  writeB(&Bbuf[0][0]);  // s_waitcnt only on bv loads

  v16i acc[2][2];
#pragma unroll
  for (int i = 0; i < 2; ++i)
#pragma unroll
    for (int j = 0; j < 2; ++j)
#pragma unroll
      for (int e = 0; e < 16; ++e) acc[i][j][e] = 0;

  for (int it = 0; it < KITERS; ++it) {
    __syncthreads();  // Bbuf[p] ready; all waves done reading Bbuf[p^1]
    const int p = it & 1;
    if (it + 1 < KITERS) {
      loadB(it + 1);         // HBM stream, flies across the MFMA phase
      loadA(it + 1, a_nxt);  // L2 hit, register prefetch
    }
    const int8_t* Bb = &Bbuf[p][0];
    const int lb = lane * 16;
#pragma unroll
    for (int ks = 0; ks < 2; ++ks) {
      const v4i b0 = *(const v4i*)(Bb + 0 * 2048 + ks * 1024 + lb);
      const v4i b1 = *(const v4i*)(Bb + 1 * 2048 + ks * 1024 + lb);
      acc[0][0] = __builtin_amdgcn_mfma_i32_32x32x32_i8(a_cur[0][ks], b0, acc[0][0], 0, 0, 0);
      acc[0][1] = __builtin_amdgcn_mfma_i32_32x32x32_i8(a_cur[0][ks], b1, acc[0][1], 0, 0, 0);
      acc[1][0] = __builtin_amdgcn_mfma_i32_32x32x32_i8(a_cur[1][ks], b0, acc[1][0], 0, 0, 0);
      acc[1][1] = __builtin_amdgcn_mfma_i32_32x32x32_i8(a_cur[1][ks], b1, acc[1][1], 0, 0, 0);
    }
    if (it + 1 < KITERS) {
      writeB(&Bbuf[p ^ 1][0]);  // waits only bv(it+1); A prefetch stays in flight
#pragma unroll
      for (int mi = 0; mi < 2; ++mi)
#pragma unroll
        for (int ks = 0; ks < 2; ++ks) a_cur[mi][ks] = a_nxt[mi][ks];
    }
  }

  // epilogue: out[m,n] = acc * ascale[m] * cscale[n] + bias[n]
  // 32x32 C/D mapping (m74/m101): col = lane&31, row = (reg&3)+8*(reg>>2)+4*(lane>>5)
#pragma unroll
  for (int mi = 0; mi < 2; ++mi)
#pragma unroll
    for (int ni = 0; ni < 2; ++ni) {
      const int n_g = n0 + ni * 32 + (lane & 31);
      const float csn = cscale[n_g];
      const float bn  = bias[n_g];
      const int mbase = 64 * wv + mi * 32 + 4 * (lane >> 5);
#pragma unroll
      for (int reg = 0; reg < 16; ++reg) {
        const int mrow = mbase + (reg & 3) + 8 * (reg >> 2);
        out[(size_t)mrow * N + n_g] =
            (float)acc[mi][ni][reg] * ldsS[mrow] * csn + bn;
      }
    }
}

// ---------------------------------------------------------------------------
extern "C" void kernel_launch(void* const* d_in, const int* in_sizes, int n_in,
                              void* d_out, int out_size, void* d_ws, size_t ws_size,
                              hipStream_t stream) {
  const float* x      = (const float*)d_in[0];   // f16 in ref -> f32 on device
  const int*   wgt    = (const int*)d_in[1];     // int8 in ref -> int32 on device
  const float* cscale = (const float*)d_in[2];
  const float* bias   = (const float*)d_in[3];   // f16 in ref -> f32 on device
  float* out = (float*)d_out;

  int8_t* q      = (int8_t*)d_ws;                            // 2 MB, pre-tiled
  float*  ascale = (float*)((int8_t*)d_ws + (size_t)M * K);  // 256 f32

  quant_kernel<<<M, 256, 0, stream>>>(x, q, ascale);
  gemm_kernel<<<N / BN, 256, 0, stream>>>(q, wgt, ascale, cscale, bias, out);
}